// Round 6
// baseline (37.764 us; speedup 1.0000x reference)
//
#include <hip/hip_runtime.h>
#include <math.h>

// YUMI left-arm FK: out[b,j] = T_static_0 Rz(a0) ... T_static_j Rz(aj), 4x4.
// Memory-bound: 117.4 MB out + 7.3 MB in; harness fill kernels sustain
// ~6.85 TB/s on this buffer => 18.2 us stream floor.
//
// R6 = R5 with the nontemporal builtins applied through a native clang
// ext_vector float4 (HIP_vector_type isn't accepted by the builtin).
// Structure = R3 (best: 24.7 us): row-parallel decomposition — row r of T_j
// depends only on row r of T_{j-1}, so 4 lanes per element each propagate ONE
// 1x4 row (~16 FMA/joint). Each 4-lane group stores one contiguous 64B
// segment per joint (R4 proved LDS-staged fully-dense stores are NOT faster:
// TCC merges this pattern already). nt flag: write-once data, skip L2
// retention.

typedef float f32x4 __attribute__((ext_vector_type(4)));

struct Statics { float m[7][12]; };  // 3x4 row-major per joint

#define TPB 256

__global__ __launch_bounds__(TPB) void fk_kernel(
    const float* __restrict__ eulers, float* __restrict__ out,
    Statics st, int B)
{
    const int gid = blockIdx.x * TPB + (int)threadIdx.x;
    const int e = gid >> 2;   // batch element
    const int r = gid & 3;    // output row this lane owns
    if (e >= B) return;

    const float* a = eulers + (size_t)e * 7;

    // Trow = row r of identity.
    float t0 = (r == 0) ? 1.f : 0.f;
    float t1 = (r == 1) ? 1.f : 0.f;
    float t2 = (r == 2) ? 1.f : 0.f;
    float t3 = (r == 3) ? 1.f : 0.f;

    // f32x4 index: e*28 + r, advancing 4 vectors (=64B) per joint.
    f32x4* obase = reinterpret_cast<f32x4*>(out) + (size_t)e * 28 + r;

    #pragma unroll
    for (int j = 0; j < 7; ++j) {
        float s, c;
        __sincosf(__builtin_nontemporal_load(a + j), &s, &c);
        const float* S = st.m[j];  // kernarg -> SGPRs

        // Trow <- Trow @ (S @ Rz(a)); rotation factored after the static
        // contraction (u = Trow.Scol0, v = Trow.Scol1); cols 2,3 pass through.
        const float u  = fmaf(t0, S[0], fmaf(t1, S[4], t2 * S[8]));
        const float v  = fmaf(t0, S[1], fmaf(t1, S[5], t2 * S[9]));
        const float n2 = fmaf(t0, S[2], fmaf(t1, S[6], t2 * S[10]));
        const float n3 = fmaf(t0, S[3], fmaf(t1, S[7], fmaf(t2, S[11], t3)));
        t0 = fmaf(c, u, s * v);
        t1 = fmaf(c, v, -s * u);
        t2 = n2;
        t3 = n3;

        f32x4 row = { t0, t1, t2, t3 };
        __builtin_nontemporal_store(row, &obase[j * 4]);
    }
}

extern "C" void kernel_launch(void* const* d_in, const int* in_sizes, int n_in,
                              void* d_out, int out_size, void* d_ws, size_t ws_size,
                              hipStream_t stream) {
    const float* eulers = (const float*)d_in[0];
    float* out = (float*)d_out;
    const int B = in_sizes[0] / 7;

    // Host-side double-precision static transforms (graph-capture-safe kernarg).
    static const double TRANS[7][3] = {
        { 0.05355, 0.0725,  0.41492},
        { 0.03,    0.0,     0.1    },
        {-0.03,    0.17283, 0.0    },
        {-0.04188, 0.0,     0.07873},
        { 0.0405,  0.16461, 0.0    },
        {-0.027,   0.0,     0.10039},
        { 0.027,   0.029,   0.0    },
    };
    static const double RPY[7][3] = {
        {-0.9795,    -0.5682,    2.3155},
        { 1.5707963,  0.0,       0.0   },
        {-1.5707963,  0.0,       0.0   },
        { 1.5707963, -1.5707963, 0.0   },
        {-1.5707963,  0.0,       0.0   },
        { 1.5707963,  0.0,       0.0   },
        {-1.5707963,  0.0,       0.0   },
    };

    Statics st;
    for (int j = 0; j < 7; ++j) {
        const double r = RPY[j][0], p = RPY[j][1], y = RPY[j][2];
        const double cr = cos(r), sr = sin(r);
        const double cp = cos(p), sp = sin(p);
        const double cy = cos(y), sy = sin(y);
        const double R[3][3] = {
            { cy*cp, cy*sp*sr - sy*cr, cy*sp*cr + sy*sr },
            { sy*cp, sy*sp*sr + cy*cr, sy*sp*cr - cy*sr },
            { -sp,   cp*sr,            cp*cr            },
        };
        for (int rr = 0; rr < 3; ++rr) {
            for (int cc = 0; cc < 3; ++cc) st.m[j][rr*4+cc] = (float)R[rr][cc];
            st.m[j][rr*4+3] = (float)TRANS[j][rr];
        }
    }

    const long long threads = (long long)B * 4;
    const int grid = (int)((threads + TPB - 1) / TPB);
    hipLaunchKernelGGL(fk_kernel, dim3(grid), dim3(TPB), 0, stream, eulers, out, st, B);
}

// Round 7
// 24.718 us; speedup vs baseline: 1.5278x; 1.5278x over previous
//
#include <hip/hip_runtime.h>
#include <math.h>

// YUMI left-arm FK: out[b,j] = T_static_0 Rz(a0) ... T_static_j Rz(aj), 4x4.
// Memory-bound: 117.4 MB out + 7.3 MB in; harness fill kernels sustain
// ~6.9 TB/s on this buffer => 18.2 us stream floor. Best measured: 24.7 us
// (this exact kernel, R3) = stream + dispatch ramp/overhead.
//
// Experiments that did NOT beat this structure:
//   R4: LDS-staged fully-dense copy-out -> 25.8 us (TCC already merges the
//       64B-segment pattern; per-inst line coverage irrelevant).
//   R6: nontemporal stores -> 37.8 us (nt bypasses the L2 write-combining
//       that makes this pattern efficient; partial lines hit HBM).
//
// Structure: row-parallel decomposition. Row r of T_j depends only on row r
// of T_{j-1} (row_r(A@B) = row_r(A)@B), so 4 lanes per element each propagate
// ONE 1x4 row (~16 FMA/joint). Lane r=3 stays (0,0,0,1) for free. Each 4-lane
// group stores one contiguous 64B-aligned segment per joint (448 = 7*64);
// a wave's 7 stores cover 16x448B dense. No LDS, no barriers, ~30 VGPR ->
// full occupancy.

struct Statics { float m[7][12]; };  // 3x4 row-major per joint

#define TPB 256

__global__ __launch_bounds__(TPB) void fk_kernel(
    const float* __restrict__ eulers, float* __restrict__ out,
    Statics st, int B)
{
    const int gid = blockIdx.x * TPB + (int)threadIdx.x;
    const int e = gid >> 2;   // batch element
    const int r = gid & 3;    // output row this lane owns
    if (e >= B) return;

    const float* a = eulers + (size_t)e * 7;

    // Trow = row r of identity.
    float t0 = (r == 0) ? 1.f : 0.f;
    float t1 = (r == 1) ? 1.f : 0.f;
    float t2 = (r == 2) ? 1.f : 0.f;
    float t3 = (r == 3) ? 1.f : 0.f;

    // float4 index: e*28 + r, advancing 4 float4 (=64B) per joint.
    float4* obase = reinterpret_cast<float4*>(out) + (size_t)e * 28 + r;

    #pragma unroll
    for (int j = 0; j < 7; ++j) {
        float s, c;
        __sincosf(a[j], &s, &c);
        const float* S = st.m[j];  // kernarg -> SGPRs

        // Trow <- Trow @ (S @ Rz(a)); rotation factored after the static
        // contraction (u = Trow.Scol0, v = Trow.Scol1); cols 2,3 pass through.
        const float u  = fmaf(t0, S[0], fmaf(t1, S[4], t2 * S[8]));
        const float v  = fmaf(t0, S[1], fmaf(t1, S[5], t2 * S[9]));
        const float n2 = fmaf(t0, S[2], fmaf(t1, S[6], t2 * S[10]));
        const float n3 = fmaf(t0, S[3], fmaf(t1, S[7], fmaf(t2, S[11], t3)));
        t0 = fmaf(c, u, s * v);
        t1 = fmaf(c, v, -s * u);
        t2 = n2;
        t3 = n3;

        obase[j * 4] = make_float4(t0, t1, t2, t3);
    }
}

extern "C" void kernel_launch(void* const* d_in, const int* in_sizes, int n_in,
                              void* d_out, int out_size, void* d_ws, size_t ws_size,
                              hipStream_t stream) {
    const float* eulers = (const float*)d_in[0];
    float* out = (float*)d_out;
    const int B = in_sizes[0] / 7;

    // Host-side double-precision static transforms (graph-capture-safe kernarg).
    static const double TRANS[7][3] = {
        { 0.05355, 0.0725,  0.41492},
        { 0.03,    0.0,     0.1    },
        {-0.03,    0.17283, 0.0    },
        {-0.04188, 0.0,     0.07873},
        { 0.0405,  0.16461, 0.0    },
        {-0.027,   0.0,     0.10039},
        { 0.027,   0.029,   0.0    },
    };
    static const double RPY[7][3] = {
        {-0.9795,    -0.5682,    2.3155},
        { 1.5707963,  0.0,       0.0   },
        {-1.5707963,  0.0,       0.0   },
        { 1.5707963, -1.5707963, 0.0   },
        {-1.5707963,  0.0,       0.0   },
        { 1.5707963,  0.0,       0.0   },
        {-1.5707963,  0.0,       0.0   },
    };

    Statics st;
    for (int j = 0; j < 7; ++j) {
        const double r = RPY[j][0], p = RPY[j][1], y = RPY[j][2];
        const double cr = cos(r), sr = sin(r);
        const double cp = cos(p), sp = sin(p);
        const double cy = cos(y), sy = sin(y);
        const double R[3][3] = {
            { cy*cp, cy*sp*sr - sy*cr, cy*sp*cr + sy*sr },
            { sy*cp, sy*sp*sr + cy*cr, sy*sp*cr - cy*sr },
            { -sp,   cp*sr,            cp*cr            },
        };
        for (int rr = 0; rr < 3; ++rr) {
            for (int cc = 0; cc < 3; ++cc) st.m[j][rr*4+cc] = (float)R[rr][cc];
            st.m[j][rr*4+3] = (float)TRANS[j][rr];
        }
    }

    const long long threads = (long long)B * 4;
    const int grid = (int)((threads + TPB - 1) / TPB);
    hipLaunchKernelGGL(fk_kernel, dim3(grid), dim3(TPB), 0, stream, eulers, out, st, B);
}